// Round 1
// 3683.365 us; speedup vs baseline: 1.2294x; 1.2294x over previous
//
#include <hip/hip_runtime.h>
#include <math.h>

#define TT 512
#define DD 768
#define NHH 12
#define NGG 4
#define HDD 64
#define FFF 2048
#define CCH 1536
#define SEQ 2048
#define NL 26
#define VOC 32000

typedef short bh8 __attribute__((ext_vector_type(8)));
typedef float f32x4 __attribute__((ext_vector_type(4)));

__device__ __forceinline__ float fast_tanh(float x) {
    float e = __expf(2.0f * x);
    return 1.0f - 2.0f / (e + 1.0f);
}

// fp32 -> bf16 (RNE) as raw short
__device__ __forceinline__ short f2bf(float f) {
    union { float f; unsigned u; } v;
    v.f = f;
    unsigned r = v.u + 0x7fffu + ((v.u >> 16) & 1u);
    return (short)(r >> 16);
}

struct __align__(8) S4 { short v[4]; };
struct __align__(16) S8 { short v[8]; };

// async global->LDS, 16 bytes per lane
__device__ __forceinline__ void gll16(const short* g, short* l) {
    __builtin_amdgcn_global_load_lds(
        (const __attribute__((address_space(1))) void*)g,
        (__attribute__((address_space(3))) void*)l, 16, 0, 0);
}

// swizzled LDS short-index for (row r in tile, logical 8-short block b), 64-short rows
#define FIDX(r, b) ((r) * 64 + ((((b) ^ ((r) & 7))) * 8))

// ---------------- rmsnorm: out(bf16) = rms_norm(in, w) ----------------
__global__ __launch_bounds__(256) void rmsnorm_k(const float* __restrict__ in,
                                                 const float* __restrict__ w,
                                                 short* __restrict__ out) {
    int t = blockIdx.x, tid = threadIdx.x;
    const float* row = in + (size_t)t * DD;
    float x0 = row[tid], x1 = row[tid + 256], x2 = row[tid + 512];
    float s = x0 * x0 + x1 * x1 + x2 * x2;
#pragma unroll
    for (int o = 32; o > 0; o >>= 1) s += __shfl_xor(s, o);
    __shared__ float red[4];
    if ((tid & 63) == 0) red[tid >> 6] = s;
    __syncthreads();
    s = red[0] + red[1] + red[2] + red[3];
    float r = rsqrtf(s / 768.0f + 1e-6f);
    short* orow = out + (size_t)t * DD;
    orow[tid]       = f2bf(x0 * r * (1.0f + w[tid]));
    orow[tid + 256] = f2bf(x1 * r * (1.0f + w[tid + 256]));
    orow[tid + 512] = f2bf(x2 * r * (1.0f + w[tid + 512]));
}

// ---------------- addnorm: h += rms_norm(in, w) ----------------
__global__ __launch_bounds__(256) void addnorm_k(float* __restrict__ h,
                                                 const float* __restrict__ in,
                                                 const float* __restrict__ w) {
    int t = blockIdx.x, tid = threadIdx.x;
    const float* row = in + (size_t)t * DD;
    float x0 = row[tid], x1 = row[tid + 256], x2 = row[tid + 512];
    float s = x0 * x0 + x1 * x1 + x2 * x2;
#pragma unroll
    for (int o = 32; o > 0; o >>= 1) s += __shfl_xor(s, o);
    __shared__ float red[4];
    if ((tid & 63) == 0) red[tid >> 6] = s;
    __syncthreads();
    s = red[0] + red[1] + red[2] + red[3];
    float r = rsqrtf(s / 768.0f + 1e-6f);
    float* hrow = h + (size_t)t * DD;
    hrow[tid]       += x0 * r * (1.0f + w[tid]);
    hrow[tid + 256] += x1 * r * (1.0f + w[tid + 256]);
    hrow[tid + 512] += x2 * r * (1.0f + w[tid + 512]);
}

// ---- weight transpose+convert: w [K][N] fp32 -> wT [N][K] bf16. grid (N/64,K/64,1|2)
__global__ __launch_bounds__(256) void wtrans(const float* __restrict__ w0, short* __restrict__ o0,
                                              const float* __restrict__ w1, short* __restrict__ o1,
                                              int N, int K) {
    const float* w = blockIdx.z ? w1 : w0;
    short* o = blockIdx.z ? o1 : o0;
    int n0 = blockIdx.x * 64, k0 = blockIdx.y * 64;
    __shared__ short t[64][72];
    int tid = threadIdx.x;
#pragma unroll
    for (int it = 0; it < 4; it++) {
        int kr = (tid >> 4) + it * 16, nc = (tid & 15) * 4;
        float4 v = *(const float4*)&w[(size_t)(k0 + kr) * N + n0 + nc];
        S4 p; p.v[0] = f2bf(v.x); p.v[1] = f2bf(v.y); p.v[2] = f2bf(v.z); p.v[3] = f2bf(v.w);
        *(S4*)&t[kr][nc] = p;
    }
    __syncthreads();
#pragma unroll
    for (int it = 0; it < 2; it++) {
        int nr = tid >> 2, kb2 = (tid & 3) * 16 + it * 8;
        S8 p;
#pragma unroll
        for (int j = 0; j < 8; j++) p.v[j] = t[kb2 + j][nr];
        *(S8*)&o[(size_t)(n0 + nr) * K + k0 + kb2] = p;
    }
}

// ---- convert KV caches to bf16 (K: [g][s][d] straight; V: [g][d][s] straight) ----
__global__ __launch_bounds__(256) void cvt_kv(const float* __restrict__ kc,
                                              const float* __restrict__ vc,
                                              short* __restrict__ kb,
                                              short* __restrict__ vb) {
    int idx = blockIdx.x * 256 + threadIdx.x;
    if (idx < 98304) {
        int e = idx * 4;
        int g = e / 98304, off = e % 98304;
        float4 v = *(const float4*)&kc[(size_t)g * 98304 + off];
        S4 p; p.v[0] = f2bf(v.x); p.v[1] = f2bf(v.y); p.v[2] = f2bf(v.z); p.v[3] = f2bf(v.w);
        *(S4*)&kb[(size_t)g * (SEQ * HDD) + off] = p;
    } else {
        int e = (idx - 98304) * 4;
        int row = e / CCH, c = e % CCH;
        float4 v = *(const float4*)&vc[(size_t)row * CCH + c];
        S4 p; p.v[0] = f2bf(v.x); p.v[1] = f2bf(v.y); p.v[2] = f2bf(v.z); p.v[3] = f2bf(v.w);
        *(S4*)&vb[(size_t)row * SEQ + c] = p;
    }
}

// ------- qkv post: per-head rmsnorm (q,k) + rope, scatter q16 / kb / vb (bf16) -------
__global__ __launch_bounds__(256) void qkv_post(const float* __restrict__ qkv,
                                                const float* __restrict__ qnw,
                                                const float* __restrict__ knw,
                                                const float* __restrict__ cosp,
                                                const float* __restrict__ sinp,
                                                short* __restrict__ q16,
                                                short* __restrict__ kb,
                                                short* __restrict__ vb) {
    int tid = threadIdx.x;
    int lane = tid & 63, wid = tid >> 6;
    int sg = blockIdx.x * 4 + wid;
    int t = sg / 20, slot = sg % 20;
    int g = slot / 5, r = slot % 5;
    float v = qkv[(size_t)t * 1280 + slot * 64 + lane];
    if (r == 4) {
        vb[((size_t)g * HDD + lane) * SEQ + CCH + t] = f2bf(v);
        return;
    }
    float s = v * v;
#pragma unroll
    for (int o = 32; o > 0; o >>= 1) s += __shfl_xor(s, o);
    float nv = v * rsqrtf(s / 64.0f + 1e-6f);
    const float* wn = (r < 3) ? qnw : knw;
    nv *= (1.0f + wn[lane]);
    float other = __shfl_xor(nv, 32);
    float rot = (lane < 32) ? -other : other;
    float ov = nv * cosp[t * 64 + lane] + rot * sinp[t * 64 + lane];
    if (r < 3)
        q16[(((size_t)(g * 3 + r)) * TT + t) * HDD + lane] = f2bf(ov);
    else
        kb[((size_t)g * SEQ + CCH + t) * HDD + lane] = f2bf(ov);
}

// ---------------- bf16 MFMA GEMM: C[m][n] (+)= A[m][k] * Bt[n][k] ----------------
// 64x64 tile, BK=64, 256 threads = 4 waves, each wave one 32x32 quadrant.
// global_load_lds (16B) staging, double-buffered LDS, 2-phase prefetch pipeline,
// XOR-swizzled LDS layout (inverse-swizzled source + swizzled ds_read).
template <int ATOMIC>
__global__ __launch_bounds__(256) void mgemm(const short* __restrict__ A, int lda, unsigned long long aHead,
                                             const short* __restrict__ Bt, int ldb, unsigned long long bHead, int bdiv,
                                             float* __restrict__ C, int ldc, unsigned long long cHead, int cOff,
                                             int kchunk, int nsplit) {
    int h = blockIdx.z / nsplit, kz = blockIdx.z % nsplit;
    A  += (size_t)h * aHead;
    Bt += (size_t)(h / bdiv) * bHead;
    C  += (size_t)h * cHead + (size_t)h * cOff;

    __shared__ short As[2][4096];
    __shared__ short Bs[2][4096];

    int tid = threadIdx.x;
    int m0 = blockIdx.x * 64, n0 = blockIdx.y * 64;
    int kbase = kz * kchunk;
    int lane = tid & 63, wid = tid >> 6;
    int mq = (wid >> 1) * 32, nq = (wid & 1) * 32;
    int frow = lane & 15;
    int blk = lane >> 4;  // 0..3 -> logical k block (8 shorts)

    // staging: thread tid -> LDS linear (row=tid/8, physblock=tid&7); fetch the
    // global block that belongs there under XOR swizzle (involution).
    int srow = tid >> 3, sblk = tid & 7;
    int sswz = sblk ^ (srow & 7);  // (srow+32)&7 == srow&7
    const short* Ap0 = A + (size_t)(m0 + srow) * lda + kbase + sswz * 8;
    const short* Ap1 = A + (size_t)(m0 + srow + 32) * lda + kbase + sswz * 8;
    const short* Bp0 = Bt + (size_t)(n0 + srow) * ldb + kbase + sswz * 8;
    const short* Bp1 = Bt + (size_t)(n0 + srow + 32) * ldb + kbase + sswz * 8;
    int l0 = tid * 8, l1 = 2048 + tid * 8;

    // fragment read offsets (swizzled), constant across K-steps
    int oA0a = FIDX(mq + frow, blk),      oA0b = FIDX(mq + frow, blk + 4);
    int oA1a = FIDX(mq + 16 + frow, blk), oA1b = FIDX(mq + 16 + frow, blk + 4);
    int oB0a = FIDX(nq + frow, blk),      oB0b = FIDX(nq + frow, blk + 4);
    int oB1a = FIDX(nq + 16 + frow, blk), oB1b = FIDX(nq + 16 + frow, blk + 4);

    f32x4 acc00 = {}, acc01 = {}, acc10 = {}, acc11 = {};

    int nt = kchunk / 64;

    // prologue: stage tile 0
    gll16(Ap0, &As[0][l0]);
    gll16(Ap1, &As[0][l1]);
    gll16(Bp0, &Bs[0][l0]);
    gll16(Bp1, &Bs[0][l1]);
    asm volatile("s_waitcnt vmcnt(0)" ::: "memory");
    __syncthreads();

    for (int t = 0; t < nt; t++) {
        int cur = t & 1;
        if (t + 1 < nt) {
            int ko = (t + 1) * 64;
            gll16(Ap0 + ko, &As[cur ^ 1][l0]);
            gll16(Ap1 + ko, &As[cur ^ 1][l1]);
            gll16(Bp0 + ko, &Bs[cur ^ 1][l0]);
            gll16(Bp1 + ko, &Bs[cur ^ 1][l1]);
        }
        const short* as = As[cur];
        const short* bs = Bs[cur];
        bh8 a0a = *(const bh8*)&as[oA0a];
        bh8 a0b = *(const bh8*)&as[oA0b];
        bh8 a1a = *(const bh8*)&as[oA1a];
        bh8 a1b = *(const bh8*)&as[oA1b];
        bh8 b0a = *(const bh8*)&bs[oB0a];
        bh8 b0b = *(const bh8*)&bs[oB0b];
        bh8 b1a = *(const bh8*)&bs[oB1a];
        bh8 b1b = *(const bh8*)&bs[oB1b];
        acc00 = __builtin_amdgcn_mfma_f32_16x16x32_bf16(a0a, b0a, acc00, 0, 0, 0);
        acc00 = __builtin_amdgcn_mfma_f32_16x16x32_bf16(a0b, b0b, acc00, 0, 0, 0);
        acc01 = __builtin_amdgcn_mfma_f32_16x16x32_bf16(a0a, b1a, acc01, 0, 0, 0);
        acc01 = __builtin_amdgcn_mfma_f32_16x16x32_bf16(a0b, b1b, acc01, 0, 0, 0);
        acc10 = __builtin_amdgcn_mfma_f32_16x16x32_bf16(a1a, b0a, acc10, 0, 0, 0);
        acc10 = __builtin_amdgcn_mfma_f32_16x16x32_bf16(a1b, b0b, acc10, 0, 0, 0);
        acc11 = __builtin_amdgcn_mfma_f32_16x16x32_bf16(a1a, b1a, acc11, 0, 0, 0);
        acc11 = __builtin_amdgcn_mfma_f32_16x16x32_bf16(a1b, b1b, acc11, 0, 0, 0);
        if (t + 1 < nt) {
            asm volatile("s_waitcnt vmcnt(0)" ::: "memory");
            __syncthreads();
        }
    }

    int er = (lane >> 4) * 4, ec = lane & 15;
    int grow = m0 + mq + er, gcol = n0 + nq + ec;
#pragma unroll
    for (int r = 0; r < 4; r++) {
        float v00 = acc00[r], v01 = acc01[r], v10 = acc10[r], v11 = acc11[r];
        size_t r0 = (size_t)(grow + r) * ldc, r1 = (size_t)(grow + 16 + r) * ldc;
        if (ATOMIC) {
            atomicAdd(&C[r0 + gcol], v00);
            atomicAdd(&C[r0 + gcol + 16], v01);
            atomicAdd(&C[r1 + gcol], v10);
            atomicAdd(&C[r1 + gcol + 16], v11);
        } else {
            C[r0 + gcol] = v00;
            C[r0 + gcol + 16] = v01;
            C[r1 + gcol] = v10;
            C[r1 + gcol + 16] = v11;
        }
    }
}

// ---------------- softcap + mask + softmax; fp32 scores in, bf16 probs out ----------
__global__ __launch_bounds__(256) void softcap_softmax(const float* __restrict__ sc,
                                                       const float* __restrict__ mask,
                                                       short* __restrict__ pb) {
    int t = blockIdx.x, hh = blockIdx.y, tid = threadIdx.x;
    const float* row = sc + ((size_t)hh * TT + t) * SEQ;
    const float* mrow = mask + (size_t)t * SEQ;
    float v[8];
    float mx = -1e30f;
#pragma unroll
    for (int k2 = 0; k2 < 8; k2++) {
        int s = tid + k2 * 256;
        float x = row[s] * 0.125f;
        x = 50.0f * fast_tanh(x * 0.02f);
        x += mrow[s];
        v[k2] = x;
        mx = fmaxf(mx, x);
    }
#pragma unroll
    for (int o = 32; o > 0; o >>= 1) mx = fmaxf(mx, __shfl_xor(mx, o));
    __shared__ float red[4];
    if ((tid & 63) == 0) red[tid >> 6] = mx;
    __syncthreads();
    mx = fmaxf(fmaxf(red[0], red[1]), fmaxf(red[2], red[3]));
    float sum = 0.0f;
#pragma unroll
    for (int k2 = 0; k2 < 8; k2++) {
        v[k2] = __expf(v[k2] - mx);
        sum += v[k2];
    }
#pragma unroll
    for (int o = 32; o > 0; o >>= 1) sum += __shfl_xor(sum, o);
    __syncthreads();
    if ((tid & 63) == 0) red[tid >> 6] = sum;
    __syncthreads();
    sum = red[0] + red[1] + red[2] + red[3];
    float inv = 1.0f / sum;
    short* prow = pb + ((size_t)hh * TT + t) * SEQ;
#pragma unroll
    for (int k2 = 0; k2 < 8; k2++) prow[tid + k2 * 256] = f2bf(v[k2] * inv);
}

// ---------------- gact = gelu(gate) * up (bf16 out); fused [512][4096] input ------
__global__ __launch_bounds__(256) void gelu_mul_k(const float* __restrict__ gu,
                                                  short* __restrict__ o) {
    size_t i = (size_t)blockIdx.x * 256 + threadIdx.x;
    int t = (int)(i >> 11), f = (int)(i & 2047);
    float x = gu[(size_t)t * 4096 + f];
    float u = gu[(size_t)t * 4096 + 2048 + f];
    float inner = 0.7978845608028654f * (x + 0.044715f * x * x * x);
    o[i] = f2bf(0.5f * x * (1.0f + fast_tanh(inner)) * u);
}

// ---------------- fp32 -> bf16 convert (float4 granularity) ----------------
__global__ __launch_bounds__(256) void cvt_bf16_k(const float* __restrict__ in,
                                                  short* __restrict__ out) {
    int i = blockIdx.x * 256 + threadIdx.x;
    float4 v = ((const float4*)in)[i];
    S4 p; p.v[0] = f2bf(v.x); p.v[1] = f2bf(v.y); p.v[2] = f2bf(v.z); p.v[3] = f2bf(v.w);
    ((S4*)out)[i] = p;
}

// ---------------- zero a float4 region ----------------
__global__ __launch_bounds__(256) void zero4_k(float4* __restrict__ p) {
    p[(size_t)blockIdx.x * 256 + threadIdx.x] = make_float4(0.f, 0.f, 0.f, 0.f);
}

// ---------------- workspace offsets ----------------
// fp32 region (floats)
#define OFF_H    0u
#define OFF_X    393216u
#define OFF_QKV  786432u
#define OFF_ATTN 1441792u
#define OFF_AO   1835008u
#define OFF_FFO  2228224u
#define OFF_GATE 2621440u
#define OFF_UP   3670016u
#define OFF_SC   4718592u
#define F32_END  17301504u
// bf16 region (shorts, from bws)
#define BO_Q16   0u
#define BO_KB    393216u
#define BO_VB    917504u
#define BO_PB    1441792u
#define BO_GACT  14024704u
#define BO_WQ    15073280u
#define BO_WO    16056320u
#define BO_WG    16646144u
#define BO_WU    18219008u
#define BO_WD    19791872u
#define BO_LMT   21364736u
// end: 45940736 shorts; total ws ~161 MB

extern "C" void kernel_launch(void* const* d_in, const int* in_sizes, int n_in,
                              void* d_out, int out_size, void* d_ws, size_t ws_size,
                              hipStream_t stream) {
    const float* emb          = (const float*)d_in[0];
    const float* kcache       = (const float*)d_in[1];
    const float* vcache       = (const float*)d_in[2];
    const float* pre_attn_w   = (const float*)d_in[3];
    const float* w_qkv        = (const float*)d_in[4];
    const float* q_norm_w     = (const float*)d_in[5];
    const float* k_norm_w     = (const float*)d_in[6];
    const float* w_out        = (const float*)d_in[7];
    const float* post_attn_w  = (const float*)d_in[8];
    const float* pre_ff_w     = (const float*)d_in[9];
    const float* w_gate       = (const float*)d_in[10];
    const float* w_up         = (const float*)d_in[11];
    const float* w_down       = (const float*)d_in[12];
    const float* post_ff_w    = (const float*)d_in[13];
    const float* final_norm_w = (const float*)d_in[14];
    const float* w_lm         = (const float*)d_in[15];
    const float* pe_cos       = (const float*)d_in[16];
    const float* pe_sin       = (const float*)d_in[17];
    const float* pel_cos      = (const float*)d_in[18];
    const float* pel_sin      = (const float*)d_in[19];
    const float* mask_g       = (const float*)d_in[20];
    const float* mask_l       = (const float*)d_in[21];

    float* ws   = (float*)d_ws;
    float* h    = ws + OFF_H;
    short* xb   = (short*)(ws + OFF_X);          // bf16 rmsnorm output (A operand)
    float* qkv  = ws + OFF_QKV;
    float* attn = ws + OFF_ATTN;
    float* ao   = ws + OFF_AO;
    float* ffo  = ws + OFF_FFO;
    float* gate = ws + OFF_GATE;                 // fused gate|up, [512][4096]
    float* sc   = ws + OFF_SC;
    short* attnb= (short*)(ws + OFF_SC);         // bf16 attn (sc region free after softmax)
    short* bws  = (short*)(ws + F32_END);
    short* q16  = bws + BO_Q16;
    short* kb   = bws + BO_KB;
    short* vb   = bws + BO_VB;
    short* pb   = bws + BO_PB;
    short* gact = bws + BO_GACT;
    short* wqT  = bws + BO_WQ;
    short* woT  = bws + BO_WO;
    short* wgT  = bws + BO_WG;                   // wgT and wuT contiguous: [4096][768]
    short* wuT  = bws + BO_WU;
    short* wdT  = bws + BO_WD;
    short* lmT  = bws + BO_LMT;
    float* out  = (float*)d_out;

    hipMemcpyAsync(h, emb, (size_t)TT * DD * sizeof(float), hipMemcpyDeviceToDevice, stream);

    for (int i = 0; i < NL; i++) {
        bool is_local = ((i + 1) % 6 == 0);
        const float* cosp  = is_local ? pel_cos : pe_cos;
        const float* sinp  = is_local ? pel_sin : pe_sin;
        const float* maskp = is_local ? mask_l : mask_g;
        const float* wqkv_i  = w_qkv  + (size_t)i * DD * 1280;
        const float* wout_i  = w_out  + (size_t)i * DD * DD;
        const float* wgate_i = w_gate + (size_t)i * DD * FFF;
        const float* wup_i   = w_up   + (size_t)i * DD * FFF;
        const float* wdown_i = w_down + (size_t)i * FFF * DD;
        const float* kc_i = kcache + (size_t)i * NGG * CCH * HDD;
        const float* vc_i = vcache + (size_t)i * NGG * HDD * CCH;

        // zero atomic-accum buffers attn/ao/ffo (contiguous, 294912 float4)
        zero4_k<<<1152, 256, 0, stream>>>((float4*)(ws + OFF_ATTN));

        // pre-attn norm -> bf16
        rmsnorm_k<<<TT, 256, 0, stream>>>(h, pre_attn_w + (size_t)i * DD, xb);

        // transpose+convert qkv weights: [768][1280] -> [1280][768] bf16
        wtrans<<<dim3(20, 12, 1), 256, 0, stream>>>(wqkv_i, wqT, wqkv_i, wqT, 1280, DD);

        // qkv = xb @ w_qkv  (M=512,N=1280,K=768)
        mgemm<0><<<dim3(8, 20, 1), 256, 0, stream>>>(xb, DD, 0ull, wqT, DD, 0ull, 1,
                                                     qkv, 1280, 0ull, 0, 768, 1);

        // convert KV caches to bf16 (natural layouts are already B^T)
        cvt_kv<<<768, 256, 0, stream>>>(kc_i, vc_i, kb, vb);

        // per-head norm + rope; fills q16, and new rows of kb / cols of vb
        qkv_post<<<2560, 256, 0, stream>>>(qkv, q_norm_w + (size_t)i * HDD,
                                           k_norm_w + (size_t)i * HDD, cosp, sinp,
                                           q16, kb, vb);

        // transpose+convert w_out: [768][768] -> bf16
        wtrans<<<dim3(12, 12, 1), 256, 0, stream>>>(wout_i, woT, wout_i, woT, DD, DD);

        // scores[h] = q16[h] @ kb[g]^T  (M=512,N=2048,K=64)
        mgemm<0><<<dim3(8, 32, 12), 256, 0, stream>>>(
            q16, HDD, (unsigned long long)(TT * HDD), kb, HDD,
            (unsigned long long)(SEQ * HDD), 3, sc, SEQ,
            (unsigned long long)(TT * SEQ), 0, 64, 1);

        // softcap + mask + softmax -> bf16 probs
        softcap_softmax<<<dim3(TT, NHH), 256, 0, stream>>>(sc, maskp, pb);

        // attn[:, h*64:] += probs[h] @ vb[g]^T  (M=512,N=64,K=2048, splitK=4)
        mgemm<1><<<dim3(8, 1, NHH * 4), 256, 0, stream>>>(
            pb, SEQ, (unsigned long long)(TT * SEQ), vb, SEQ,
            (unsigned long long)(HDD * SEQ), 3, attn, DD, 0ull, 64, 512, 4);

        // attn fp32 -> bf16 (sc region is free now)
        cvt_bf16_k<<<384, 256, 0, stream>>>(attn, attnb);

        // ao = attn @ w_out  (M=512,N=768,K=768, splitK=2)
        mgemm<1><<<dim3(8, 12, 2), 256, 0, stream>>>(attnb, DD, 0ull, woT, DD, 0ull, 1,
                                                     ao, DD, 0ull, 0, 384, 2);

        addnorm_k<<<TT, 256, 0, stream>>>(h, ao, post_attn_w + (size_t)i * DD);

        // FF
        rmsnorm_k<<<TT, 256, 0, stream>>>(h, pre_ff_w + (size_t)i * DD, xb);
        wtrans<<<dim3(32, 12, 2), 256, 0, stream>>>(wgate_i, wgT, wup_i, wuT, FFF, DD);
        // fused gate|up GEMM: N=4096 (wgT and wuT contiguous), C ldc=4096
        mgemm<0><<<dim3(8, 64, 1), 256, 0, stream>>>(xb, DD, 0ull, wgT, DD, 0ull, 1,
                                                     gate, 4096, 0ull, 0, 768, 1);
        gelu_mul_k<<<4096, 256, 0, stream>>>(gate, gact);
        wtrans<<<dim3(12, 32, 1), 256, 0, stream>>>(wdown_i, wdT, wdown_i, wdT, DD, FFF);
        mgemm<1><<<dim3(8, 12, 4), 256, 0, stream>>>(gact, FFF, 0ull, wdT, FFF, 0ull, 1,
                                                     ffo, DD, 0ull, 0, 512, 4);
        addnorm_k<<<TT, 256, 0, stream>>>(h, ffo, post_ff_w + (size_t)i * DD);
    }

    // final norm + lm head
    rmsnorm_k<<<TT, 256, 0, stream>>>(h, final_norm_w, xb);
    wtrans<<<dim3(500, 12, 1), 256, 0, stream>>>(w_lm, lmT, w_lm, lmT, VOC, DD);
    mgemm<0><<<dim3(8, 500, 1), 256, 0, stream>>>(xb, DD, 0ull, lmT, DD, 0ull, 1,
                                                  out, VOC, 0ull, 0, 768, 1);
}